// Round 3
// baseline (1026.451 us; speedup 1.0000x reference)
//
#include <hip/hip_runtime.h>
#include <math.h>

// Problem constants
#define B 4
#define C 21
#define H 256
#define W 256
#define HW (H*W)            // 65536
#define NPIX (B*HW)         // 262144
#define NB (B*C*HW)         // 5505024

#define TS 16               // output tile
#define R 6                 // bilateral radius
#define TH (TS + 2*R)       // 28
#define NS (TH*TH)          // 784

// ---------------------------------------------------------------------------
// Tables: kt[0..18] normalized Gaussian taps (sigma=3), kt[19]=w0, kt[20]=1-w0,
// kt[32..200] = 13x13 bilateral spatial weights with sigma=13 (!) — the
// reference passes COLOR_SIGMA as the bilateral's spatial sigma:
//   _bilateral_message(Q, img, r, sxy=COLOR_SIGMA, srgb=COLOR_SIGMA)
__global__ void k_ktab(float* __restrict__ kt) {
    if (blockIdx.x == 0 && threadIdx.x == 0) {
        float e[19]; float s = 0.f;
        for (int i = 0; i < 19; ++i) {
            double d = (double)(i - 9);
            e[i] = (float)exp(-(d*d) / 18.0);   // gaussian term: sigma = 3
            s += e[i];
        }
        for (int i = 0; i < 19; ++i) kt[i] = e[i] / s;
        float k9 = e[9] / s;
        float w0 = k9 * k9;
        kt[19] = w0;
        kt[20] = 1.f - w0;
        for (int dy = -R; dy <= R; ++dy)
            for (int dx = -R; dx <= R; ++dx) {
                double d2 = (double)(dy*dy + dx*dx);
                kt[32 + (dy+R)*13 + (dx+R)] = (float)exp(-d2 / 338.0);  // sigma = 13
            }
    }
}

// ---------------------------------------------------------------------------
// Init: U = -log(clip(softmax(logits),1e-5,1)); Q0 = softmax(-U)
__global__ __launch_bounds__(256) void k_init(const float* __restrict__ logits,
                                              float* __restrict__ U,
                                              float* __restrict__ Q) {
    int p = blockIdx.x * 256 + threadIdx.x;
    if (p >= NPIX) return;
    int b = p >> 16;
    int rem = p & (HW - 1);
    const float* lp = logits + (size_t)b * C * HW + rem;

    float v[C];
    float m = -1e30f;
#pragma unroll
    for (int c = 0; c < C; ++c) { v[c] = lp[c*HW]; m = fmaxf(m, v[c]); }
    float s = 0.f;
#pragma unroll
    for (int c = 0; c < C; ++c) { v[c] = expf(v[c] - m); s += v[c]; }

    float u[C];
    float m2 = -1e30f;
#pragma unroll
    for (int c = 0; c < C; ++c) {
        float sm = v[c] / s;
        sm = fminf(fmaxf(sm, 1e-5f), 1.f);
        float uu = -logf(sm);
        u[c] = uu;
        m2 = fmaxf(m2, -uu);
    }
    float s2 = 0.f;
    float q[C];
#pragma unroll
    for (int c = 0; c < C; ++c) { q[c] = expf(-u[c] - m2); s2 += q[c]; }

    float* Up = U + (size_t)b * C * HW + rem;
    float* Qp = Q + (size_t)b * C * HW + rem;
#pragma unroll
    for (int c = 0; c < C; ++c) { Up[c*HW] = u[c]; Qp[c*HW] = q[c] / s2; }
}

// ---------------------------------------------------------------------------
// Gaussian horizontal pass (zero-padded)
__global__ __launch_bounds__(256) void k_gh(const float* __restrict__ Q,
                                            float* __restrict__ T,
                                            const float* __restrict__ kt) {
    __shared__ float k[19];
    if (threadIdx.x < 19) k[threadIdx.x] = kt[threadIdx.x];
    __syncthreads();
    int idx = blockIdx.x * 256 + threadIdx.x;
    if (idx >= NB) return;
    int x = idx & (W - 1);
    float acc = 0.f;
#pragma unroll
    for (int j = 0; j < 19; ++j) {
        int xx = x + j - 9;
        if (xx >= 0 && xx < W) acc = fmaf(k[j], Q[idx + j - 9], acc);
    }
    T[idx] = acc;
}

// Gaussian vertical pass + message: MG = (conv - w0*Q)/(1-w0)
__global__ __launch_bounds__(256) void k_gv(const float* __restrict__ T,
                                            const float* __restrict__ Q,
                                            float* __restrict__ MG,
                                            const float* __restrict__ kt) {
    __shared__ float k[21];
    if (threadIdx.x < 21) k[threadIdx.x] = kt[threadIdx.x];
    __syncthreads();
    int idx = blockIdx.x * 256 + threadIdx.x;
    if (idx >= NB) return;
    int y = (idx >> 8) & (H - 1);
    float acc = 0.f;
#pragma unroll
    for (int j = 0; j < 19; ++j) {
        int yy = y + j - 9;
        if (yy >= 0 && yy < H) acc = fmaf(k[j], T[idx + (j - 9) * W], acc);
    }
    MG[idx] = (acc - k[19] * Q[idx]) / k[20];
}

// ---------------------------------------------------------------------------
// Bilateral message + mean-field update:
//   Qn = softmax(-U + 3*MG + 10*mb), mb = bilateral(Q, img)
__global__ __launch_bounds__(256) void k_update(const float* __restrict__ Q,
                                                const float* __restrict__ U,
                                                const float* __restrict__ MG,
                                                const float* __restrict__ images,
                                                const float* __restrict__ kt,
                                                float* __restrict__ Qn) {
    // Pixel-major LDS: 784 pixels x 24 floats (ch0..20 = Q, 21..23 = img)
    __shared__ float4 lds[NS * 6];
    __shared__ float sws[169];

    int blk = blockIdx.x;
    int b = blk >> 8;           // 256 tiles per image
    int tile = blk & 255;
    int ty0 = (tile >> 4) * TS;
    int tx0 = (tile & 15) * TS;
    int tid = threadIdx.x;

    const float* Qb = Q + (size_t)b * C * HW;
    const float* Ib = images + (size_t)b * 3 * HW;

    if (tid < 169) sws[tid] = kt[32 + tid];

    // Stage halo tile (zero padding outside image)
    for (int s = tid; s < NS; s += 256) {
        int ly = s / TH;
        int lx = s - ly * TH;
        int gy = ty0 + ly - R;
        int gx = tx0 + lx - R;
        bool in = (gy >= 0) && (gy < H) && (gx >= 0) && (gx < W);
        int g = gy * W + gx;
        float4 v[6];
        float* vf = (float*)v;
#pragma unroll
        for (int c = 0; c < C; ++c) vf[c] = in ? Qb[c*HW + g] : 0.f;
#pragma unroll
        for (int c = 0; c < 3; ++c) {
            float im = in ? Ib[c*HW + g] : 0.f;
            vf[21 + c] = floorf(fminf(fmaxf(im * 255.f, 0.f), 255.f));
        }
#pragma unroll
        for (int j = 0; j < 6; ++j) lds[s * 6 + j] = v[j];
    }
    __syncthreads();

    int ty = tid >> 4, tx = tid & 15;
    int cy = ty + R, cx = tx + R;
    int cbase = (cy * TH + cx) * 6;

    float4 c5 = lds[cbase + 5];
    float cr = c5.y, cg = c5.z, cb = c5.w;

    float msg[C];
#pragma unroll
    for (int c = 0; c < C; ++c) msg[c] = 0.f;
    float wsum = 0.f;

    for (int dy = -R; dy <= R; ++dy) {
        int rowp = (cy + dy) * TH + cx;
        const float* swrow = &sws[(dy + R) * 13 + R];
#pragma unroll
        for (int dx = -R; dx <= R; ++dx) {
            int p = (rowp + dx) * 6;
            float4 t[6];
#pragma unroll
            for (int j = 0; j < 6; ++j) t[j] = lds[p + j];
            const float* qv = (const float*)t;
            float dr = cr - qv[21];
            float dg = cg - qv[22];
            float db = cb - qv[23];
            float ss = dr*dr + dg*dg + db*db;
            float cw = expf(-ss / 338.f);
            float sw = swrow[dx];
            if (dy == 0 && dx == 0) sw = 0.f;      // exact center exclusion
            float w = sw * cw;
            wsum += w;
#pragma unroll
            for (int c = 0; c < C; ++c) msg[c] = fmaf(w, qv[c], msg[c]);
        }
    }

    float denom = wsum + 1e-8f;
    const float* Up = U + (size_t)b * C * HW;
    const float* Mp = MG + (size_t)b * C * HW;
    float* Qp = Qn + (size_t)b * C * HW;
    int g = (ty0 + ty) * W + (tx0 + tx);

    float sv[C];
    float m = -1e30f;
#pragma unroll
    for (int c = 0; c < C; ++c) {
        float mb = msg[c] / denom;
        float val = -Up[c*HW + g] + 3.0f * Mp[c*HW + g] + 10.0f * mb;
        sv[c] = val;
        m = fmaxf(m, val);
    }
    float s = 0.f;
#pragma unroll
    for (int c = 0; c < C; ++c) { sv[c] = expf(sv[c] - m); s += sv[c]; }
#pragma unroll
    for (int c = 0; c < C; ++c) Qp[c*HW + g] = sv[c] / s;
}

// ---------------------------------------------------------------------------
// Loss: per-pixel NLL of log_softmax(log(Q+1e-8)) at label; block partial sums
__global__ __launch_bounds__(256) void k_loss(const float* __restrict__ Q,
                                              const int* __restrict__ labels,
                                              float* __restrict__ part) {
    int p = blockIdx.x * 256 + threadIdx.x;
    float nll = 0.f;
    if (p < NPIX) {
        int b = p >> 16;
        int rem = p & (HW - 1);
        const float* Qp = Q + (size_t)b * C * HW + rem;
        int lab = labels[p];
        float s = 0.f, ql = 1e-8f;
#pragma unroll
        for (int c = 0; c < C; ++c) {
            float q = Qp[c*HW] + 1e-8f;
            s += q;
            ql = (c == lab) ? q : ql;
        }
        nll = -(logf(ql) - logf(s));
    }
#pragma unroll
    for (int off = 32; off > 0; off >>= 1) nll += __shfl_down(nll, off);
    __shared__ float red[4];
    int lane = threadIdx.x & 63, wv = threadIdx.x >> 6;
    if (lane == 0) red[wv] = nll;
    __syncthreads();
    if (threadIdx.x == 0) part[blockIdx.x] = red[0] + red[1] + red[2] + red[3];
}

__global__ __launch_bounds__(256) void k_final(const float* __restrict__ part,
                                               float* __restrict__ out) {
    int tid = threadIdx.x;
    float s = part[tid] + part[tid + 256] + part[tid + 512] + part[tid + 768];
#pragma unroll
    for (int off = 32; off > 0; off >>= 1) s += __shfl_down(s, off);
    __shared__ float red[4];
    int lane = tid & 63, wv = tid >> 6;
    if (lane == 0) red[wv] = s;
    __syncthreads();
    if (tid == 0) out[0] = (red[0] + red[1] + red[2] + red[3]) / (float)NPIX;
}

// ---------------------------------------------------------------------------
extern "C" void kernel_launch(void* const* d_in, const int* in_sizes, int n_in,
                              void* d_out, int out_size, void* d_ws, size_t ws_size,
                              hipStream_t stream) {
    const float* logits = (const float*)d_in[0];
    const float* images = (const float*)d_in[1];
    const int*   labels = (const int*)d_in[2];
    float* out = (float*)d_out;

    float* ws = (float*)d_ws;
    float* Ubuf = ws;                       // NB
    float* Abuf = ws + (size_t)NB;          // NB  (Q ping)
    float* Bbuf = ws + 2*(size_t)NB;        // NB  (Q pong / gaussian tmp)
    float* Mbuf = ws + 3*(size_t)NB;        // NB  (gaussian message)
    float* KT   = ws + 4*(size_t)NB;        // 256 floats
    float* PART = KT + 256;                 // 1024 floats

    k_ktab<<<1, 64, 0, stream>>>(KT);
    k_init<<<NPIX/256, 256, 0, stream>>>(logits, Ubuf, Abuf);

    float* cur = Abuf;
    float* oth = Bbuf;
    for (int it = 0; it < 5; ++it) {
        k_gh<<<NB/256, 256, 0, stream>>>(cur, oth, KT);
        k_gv<<<NB/256, 256, 0, stream>>>(oth, cur, Mbuf, KT);
        k_update<<<B*256, 256, 0, stream>>>(cur, Ubuf, Mbuf, images, KT, oth);
        float* t = cur; cur = oth; oth = t;
    }

    k_loss<<<NPIX/256, 256, 0, stream>>>(cur, labels, PART);
    k_final<<<1, 256, 0, stream>>>(PART, out);
    (void)in_sizes; (void)n_in; (void)out_size; (void)ws_size;
}

// Round 4
// 511.194 us; speedup vs baseline: 2.0079x; 2.0079x over previous
//
#include <hip/hip_runtime.h>
#include <hip/hip_fp16.h>
#include <math.h>

// Problem constants
#define B 4
#define C 21
#define NP 11               // f16 channel pairs (ch 2k, 2k+1; pair 10 high = pad 0)
#define H 256
#define W 256
#define HW (H*W)            // 65536
#define NPIX (B*HW)         // 262144
#define NB (B*C*HW)         // 5505024   (f32 U elements)
#define NB2 (B*NP*HW)       // 2883584   (packed uint elements)

#define TS 16               // output tile
#define R 6                 // bilateral radius
#define TH (TS + 2*R)       // 28
#define NS (TH*TH)          // 784

union U4 { uint4 u; __half2 h[4]; };
union Hu { unsigned int u32; __half2 h; };

// ---------------------------------------------------------------------------
// Tables: kt[0..18] gaussian taps (sigma=3), kt[19]=w0, kt[20]=1-w0,
// kt[32..200] = 13x13 bilateral spatial weights, sigma=13 (reference passes
// COLOR_SIGMA as the bilateral's spatial sigma).
__global__ void k_ktab(float* __restrict__ kt) {
    int t = threadIdx.x;
    if (t < 169) {
        int dy = t / 13 - 6, dx = t % 13 - 6;
        kt[32 + t] = (float)exp(-(double)(dy*dy + dx*dx) / 338.0);
    }
    if (t == 200) {
        float e[19]; float s = 0.f;
        for (int i = 0; i < 19; ++i) {
            double d = (double)(i - 9);
            e[i] = (float)exp(-(d*d) / 18.0);
            s += e[i];
        }
        for (int i = 0; i < 19; ++i) kt[i] = e[i] / s;
        float k9 = e[9] / s;
        kt[19] = k9 * k9;
        kt[20] = 1.f - k9 * k9;
    }
}

// ---------------------------------------------------------------------------
// Pre-quantize image once: IQ[p] = (floor(clip(img*255)), ..., 0)
__global__ __launch_bounds__(256) void k_prep(const float* __restrict__ img,
                                              float4* __restrict__ IQ) {
    int p = blockIdx.x * 256 + threadIdx.x;
    int b = p >> 16, g = p & (HW - 1);
    const float* ib = img + (size_t)b * 3 * HW + g;
    float r  = floorf(fminf(fmaxf(ib[0]      * 255.f, 0.f), 255.f));
    float gg = floorf(fminf(fmaxf(ib[HW]     * 255.f, 0.f), 255.f));
    float bb = floorf(fminf(fmaxf(ib[2*HW]   * 255.f, 0.f), 255.f));
    IQ[p] = make_float4(r, gg, bb, 0.f);
}

// ---------------------------------------------------------------------------
// Init: U = -log(clip(softmax(logits),1e-5,1)) (f32); Q0 = softmax(-U) packed f16
__global__ __launch_bounds__(256) void k_init(const float* __restrict__ logits,
                                              float* __restrict__ U,
                                              unsigned int* __restrict__ Qp) {
    int p = blockIdx.x * 256 + threadIdx.x;
    int b = p >> 16, g = p & (HW - 1);
    const float* lp = logits + (size_t)b * C * HW + g;

    float v[C];
    float m = -1e30f;
#pragma unroll
    for (int c = 0; c < C; ++c) { v[c] = lp[c*HW]; m = fmaxf(m, v[c]); }
    float s = 0.f;
#pragma unroll
    for (int c = 0; c < C; ++c) { v[c] = __expf(v[c] - m); s += v[c]; }
    float inv = 1.f / s;

    float u[C];
    float m2 = -1e30f;
#pragma unroll
    for (int c = 0; c < C; ++c) {
        float sm = fminf(fmaxf(v[c] * inv, 1e-5f), 1.f);
        float uu = -__logf(sm);
        u[c] = uu;
        m2 = fmaxf(m2, -uu);
    }
    float s2 = 0.f;
    float q[C];
#pragma unroll
    for (int c = 0; c < C; ++c) { q[c] = __expf(-u[c] - m2); s2 += q[c]; }
    float inv2 = 1.f / s2;

    float* Up = U + (size_t)b * C * HW + g;
    unsigned int* Qb = Qp + (size_t)b * NP * HW + g;
#pragma unroll
    for (int c = 0; c < C; ++c) Up[c*HW] = u[c];
#pragma unroll
    for (int k = 0; k < NP; ++k) {
        float a = q[2*k] * inv2;
        float bb = (2*k + 1 < C) ? q[2*k + 1] * inv2 : 0.f;
        Hu x; x.h = __floats2half2_rn(a, bb);
        Qb[k*HW] = x.u32;
    }
}

// ---------------------------------------------------------------------------
// Gaussian horizontal pass over packed pairs (zero-padded), float4-chunked
__global__ __launch_bounds__(256) void k_gh(const unsigned int* __restrict__ Q,
                                            unsigned int* __restrict__ T,
                                            const float* __restrict__ kt) {
    __shared__ float kf[19];
    if (threadIdx.x < 19) kf[threadIdx.x] = kt[threadIdx.x];
    __syncthreads();
    __half2 kh[19];
#pragma unroll
    for (int j = 0; j < 19; ++j) kh[j] = __float2half2_rn(kf[j]);

    int e = (blockIdx.x * 256 + threadIdx.x) * 4;    // uint index, 4-aligned in x
    int x0 = e & (W - 1);
    const unsigned int* row = Q + (e - x0);

    U4 ch[7];
#pragma unroll
    for (int c2 = 0; c2 < 7; ++c2) {
        int xb = x0 - 12 + c2 * 4;
        if ((unsigned)xb < (unsigned)W) ch[c2].u = *(const uint4*)(row + xb);
        else ch[c2].u = make_uint4(0,0,0,0);
    }
    const __half2* v = (const __half2*)ch;           // v[0..27] = x0-12 .. x0+15

    U4 o;
#pragma unroll
    for (int i = 0; i < 4; ++i) {
        __half2 acc = __float2half2_rn(0.f);
#pragma unroll
        for (int j = 0; j < 19; ++j) acc = __hfma2(kh[j], v[i + 3 + j], acc);
        o.h[i] = acc;
    }
    *(uint4*)(T + e) = o.u;
}

// Gaussian vertical pass + message: MG = (conv - w0*Q)*(1/(1-w0)), packed
__global__ __launch_bounds__(256) void k_gv(const unsigned int* __restrict__ T,
                                            const unsigned int* __restrict__ Q,
                                            unsigned int* __restrict__ MG,
                                            const float* __restrict__ kt) {
    __shared__ float kf[21];
    if (threadIdx.x < 21) kf[threadIdx.x] = kt[threadIdx.x];
    __syncthreads();
    __half2 kh[19];
#pragma unroll
    for (int j = 0; j < 19; ++j) kh[j] = __float2half2_rn(kf[j]);
    __half2 nw0  = __float2half2_rn(-kf[19]);
    __half2 inv1 = __float2half2_rn(1.f / kf[20]);

    int e = (blockIdx.x * 256 + threadIdx.x) * 4;
    int y = (e >> 8) & (H - 1);

    __half2 acc[4];
#pragma unroll
    for (int i = 0; i < 4; ++i) acc[i] = __float2half2_rn(0.f);
#pragma unroll
    for (int j = 0; j < 19; ++j) {
        int yy = y + j - 9;
        if ((unsigned)yy < (unsigned)H) {
            U4 f; f.u = *(const uint4*)(T + e + (j - 9) * W);
#pragma unroll
            for (int i = 0; i < 4; ++i) acc[i] = __hfma2(kh[j], f.h[i], acc[i]);
        }
    }
    U4 q; q.u = *(const uint4*)(Q + e);
    U4 o;
#pragma unroll
    for (int i = 0; i < 4; ++i)
        o.h[i] = __hmul2(__hfma2(nw0, q.h[i], acc[i]), inv1);
    *(uint4*)(MG + e) = o.u;
}

// ---------------------------------------------------------------------------
// Bilateral message + mean-field update (packed f16, conflict-free SoA LDS):
//   Qn = softmax(-U + 3*MG + 10*mb)
__global__ __launch_bounds__(256) void k_update(const unsigned int* __restrict__ Q,
                                                const float* __restrict__ U,
                                                const unsigned int* __restrict__ MG,
                                                const float4* __restrict__ IQ,
                                                const float* __restrict__ kt,
                                                unsigned int* __restrict__ Qn) {
    __shared__ uint4  QhA[NS];    // pairs 0..3  (ch 0..7)
    __shared__ uint4  QhB[NS];    // pairs 4..7  (ch 8..15)
    __shared__ uint4  QhC[NS];    // pairs 8..10 (ch 16..21) + pad
    __shared__ float4 Im[NS];     // quantized rgb
    __shared__ float  sws[169];

    int blk = blockIdx.x;
    int b = blk >> 8;
    int tile = blk & 255;
    int ty0 = (tile >> 4) * TS;
    int tx0 = (tile & 15) * TS;
    int tid = threadIdx.x;

    const unsigned int* Qb = Q + (size_t)b * NP * HW;
    const float4* Ib = IQ + (size_t)b * HW;

    if (tid < 169) sws[tid] = kt[32 + tid];

    for (int s = tid; s < NS; s += 256) {
        int ly = s / TH;
        int lx = s - ly * TH;
        int gy = ty0 + ly - R;
        int gx = tx0 + lx - R;
        bool in = ((unsigned)gy < (unsigned)H) && ((unsigned)gx < (unsigned)W);
        int g = gy * W + gx;
        unsigned int u[NP];
#pragma unroll
        for (int k = 0; k < NP; ++k) u[k] = in ? Qb[k*HW + g] : 0u;
        QhA[s] = make_uint4(u[0], u[1], u[2], u[3]);
        QhB[s] = make_uint4(u[4], u[5], u[6], u[7]);
        QhC[s] = make_uint4(u[8], u[9], u[10], 0u);
        Im[s]  = in ? Ib[g] : make_float4(0.f, 0.f, 0.f, 0.f);
    }
    __syncthreads();

    int ty = tid >> 4, tx = tid & 15;
    int cy = ty + R, cx = tx + R;
    int cpix = cy * TH + cx;

    float4 cim = Im[cpix];
    float cr = cim.x, cg = cim.y, cb = cim.z;

    __half2 m[NP];
#pragma unroll
    for (int k = 0; k < NP; ++k) m[k] = __float2half2_rn(0.f);
    float wsum = 0.f;

    for (int dy = -R; dy <= R; ++dy) {
        int rowp = (cy + dy) * TH + cx;
        const float* swrow = &sws[(dy + R) * 13 + R];
#pragma unroll
        for (int dx = -R; dx <= R; ++dx) {
            int p = rowp + dx;
            U4 a, bb, cc;
            a.u  = QhA[p];
            bb.u = QhB[p];
            cc.u = QhC[p];
            float4 im = Im[p];
            float dr = cr - im.x, dg = cg - im.y, db = cb - im.z;
            float ss = fmaf(dr, dr, fmaf(dg, dg, db * db));
            float w = swrow[dx] * __expf(ss * (-1.f / 338.f));
            if (dx == 0) { if (dy == 0) w = 0.f; }       // exact center exclusion
            wsum += w;
            __half2 wh = __float2half2_rn(w);
            m[0] = __hfma2(wh, a.h[0], m[0]);
            m[1] = __hfma2(wh, a.h[1], m[1]);
            m[2] = __hfma2(wh, a.h[2], m[2]);
            m[3] = __hfma2(wh, a.h[3], m[3]);
            m[4] = __hfma2(wh, bb.h[0], m[4]);
            m[5] = __hfma2(wh, bb.h[1], m[5]);
            m[6] = __hfma2(wh, bb.h[2], m[6]);
            m[7] = __hfma2(wh, bb.h[3], m[7]);
            m[8] = __hfma2(wh, cc.h[0], m[8]);
            m[9] = __hfma2(wh, cc.h[1], m[9]);
            m[10] = __hfma2(wh, cc.h[2], m[10]);
        }
    }

    float inv = 1.f / (wsum + 1e-8f);
    int g = (ty0 + ty) * W + (tx0 + tx);
    const float* Up = U + (size_t)b * C * HW + g;
    const unsigned int* Mp = MG + (size_t)b * NP * HW + g;
    unsigned int* Qo = Qn + (size_t)b * NP * HW + g;

    float sv[C];
    float mm = -1e30f;
#pragma unroll
    for (int k = 0; k < NP; ++k) {
        float2 mf = __half22float2(m[k]);
        Hu mgu; mgu.u32 = Mp[k*HW];
        float2 mgf = __half22float2(mgu.h);
        int c0 = 2 * k;
        float v0 = -Up[c0*HW] + 3.f * mgf.x + 10.f * (mf.x * inv);
        sv[c0] = v0; mm = fmaxf(mm, v0);
        if (c0 + 1 < C) {
            float v1 = -Up[(c0+1)*HW] + 3.f * mgf.y + 10.f * (mf.y * inv);
            sv[c0+1] = v1; mm = fmaxf(mm, v1);
        }
    }
    float s = 0.f;
#pragma unroll
    for (int c = 0; c < C; ++c) { sv[c] = __expf(sv[c] - mm); s += sv[c]; }
    float is = 1.f / s;
#pragma unroll
    for (int k = 0; k < NP; ++k) {
        float a = sv[2*k] * is;
        float bb = (2*k + 1 < C) ? sv[2*k + 1] * is : 0.f;
        Hu x; x.h = __floats2half2_rn(a, bb);
        Qo[k*HW] = x.u32;
    }
}

// ---------------------------------------------------------------------------
// Loss: per-pixel NLL of log_softmax(log(Q+1e-8)) at label; block partial sums
__global__ __launch_bounds__(256) void k_loss(const unsigned int* __restrict__ Q,
                                              const int* __restrict__ labels,
                                              float* __restrict__ part) {
    int p = blockIdx.x * 256 + threadIdx.x;
    int b = p >> 16, g = p & (HW - 1);
    const unsigned int* Qb = Q + (size_t)b * NP * HW + g;
    int lab = labels[p];
    float s = 0.f, ql = 1e-8f;
#pragma unroll
    for (int k = 0; k < NP; ++k) {
        Hu x; x.u32 = Qb[k*HW];
        float2 f = __half22float2(x.h);
        int c0 = 2 * k;
        float q0 = f.x + 1e-8f;
        s += q0;
        if (c0 == lab) ql = q0;
        if (c0 + 1 < C) {
            float q1 = f.y + 1e-8f;
            s += q1;
            if (c0 + 1 == lab) ql = q1;
        }
    }
    float nll = __logf(s) - __logf(ql);
#pragma unroll
    for (int off = 32; off > 0; off >>= 1) nll += __shfl_down(nll, off);
    __shared__ float red[4];
    int lane = threadIdx.x & 63, wv = threadIdx.x >> 6;
    if (lane == 0) red[wv] = nll;
    __syncthreads();
    if (threadIdx.x == 0) part[blockIdx.x] = red[0] + red[1] + red[2] + red[3];
}

__global__ __launch_bounds__(256) void k_final(const float* __restrict__ part,
                                               float* __restrict__ out) {
    int tid = threadIdx.x;
    float s = part[tid] + part[tid + 256] + part[tid + 512] + part[tid + 768];
#pragma unroll
    for (int off = 32; off > 0; off >>= 1) s += __shfl_down(s, off);
    __shared__ float red[4];
    int lane = tid & 63, wv = tid >> 6;
    if (lane == 0) red[wv] = s;
    __syncthreads();
    if (tid == 0) out[0] = (red[0] + red[1] + red[2] + red[3]) / (float)NPIX;
}

// ---------------------------------------------------------------------------
extern "C" void kernel_launch(void* const* d_in, const int* in_sizes, int n_in,
                              void* d_out, int out_size, void* d_ws, size_t ws_size,
                              hipStream_t stream) {
    const float* logits = (const float*)d_in[0];
    const float* images = (const float*)d_in[1];
    const int*   labels = (const int*)d_in[2];
    float* out = (float*)d_out;

    float* ws = (float*)d_ws;
    float*        Ubuf = ws;                                    // NB f32
    unsigned int* QA   = (unsigned int*)(ws + (size_t)NB);      // NB2
    unsigned int* QB   = QA + (size_t)NB2;                      // NB2 (+ gh tmp alias)
    unsigned int* Mpk  = QB + (size_t)NB2;                      // NB2
    float4*       IQ   = (float4*)(Mpk + (size_t)NB2);          // NPIX float4
    float*        KT   = (float*)(IQ + (size_t)NPIX);           // 256 f32
    float*        PART = KT + 256;                              // 1024 f32

    k_ktab<<<1, 256, 0, stream>>>(KT);
    k_prep<<<NPIX/256, 256, 0, stream>>>(images, IQ);
    k_init<<<NPIX/256, 256, 0, stream>>>(logits, Ubuf, QA);

    unsigned int* cur = QA;
    unsigned int* oth = QB;
    for (int it = 0; it < 5; ++it) {
        // gh tmp lives in the (currently dead) other Q buffer
        k_gh<<<NB2/1024, 256, 0, stream>>>(cur, oth, KT);
        k_gv<<<NB2/1024, 256, 0, stream>>>(oth, cur, Mpk, KT);
        k_update<<<B*256, 256, 0, stream>>>(cur, Ubuf, Mpk, IQ, KT, oth);
        unsigned int* t = cur; cur = oth; oth = t;
    }

    k_loss<<<NPIX/256, 256, 0, stream>>>(cur, labels, PART);
    k_final<<<1, 256, 0, stream>>>(PART, out);
    (void)in_sizes; (void)n_in; (void)out_size; (void)ws_size;
}

// Round 5
// 397.410 us; speedup vs baseline: 2.5829x; 1.2863x over previous
//
#include <hip/hip_runtime.h>
#include <hip/hip_fp16.h>
#include <math.h>

// Problem constants
#define B 4
#define C 21
#define NP 11               // f16 channel pairs (ch 2k, 2k+1; pair 10 high = spare)
#define H 256
#define W 256
#define HW (H*W)            // 65536
#define NPIX (B*HW)         // 262144
#define NB (B*C*HW)         // 5505024   (f32 U elements)
#define NB2 (B*NP*HW)       // 2883584   (packed uint elements)

#define TSX 16              // output tile x
#define TSY 32              // output tile y (2 rows per thread)
#define R 6                 // bilateral radius
#define HX (TSX + 2*R)      // 28
#define HY (TSY + 2*R)      // 44
#define NSL (HX*HY)         // 1232

#define C2F ((float)(1.4426950408889634 / 338.0))   // log2(e)/338

union U4 { uint4 u; __half2 h[4]; };
union Hu { unsigned int u32; __half2 h; };

// ---------------------------------------------------------------------------
// Gaussian taps: kt[0..18] normalized (sigma=3), kt[19]=w0, kt[20]=1-w0
__global__ void k_ktab(float* __restrict__ kt) {
    if (threadIdx.x == 0) {
        float e[19]; float s = 0.f;
        for (int i = 0; i < 19; ++i) {
            double d = (double)(i - 9);
            e[i] = (float)exp(-(d*d) / 18.0);
            s += e[i];
        }
        for (int i = 0; i < 19; ++i) kt[i] = e[i] / s;
        float k9 = e[9] / s;
        kt[19] = k9 * k9;
        kt[20] = 1.f - k9 * k9;
    }
}

// ---------------------------------------------------------------------------
// Pre-quantize image once into packed halves: (r,g),(b,0) — integers 0..255
__global__ __launch_bounds__(256) void k_prep(const float* __restrict__ img,
                                              uint2* __restrict__ IQ2) {
    int p = blockIdx.x * 256 + threadIdx.x;
    int b = p >> 16, g = p & (HW - 1);
    const float* ib = img + (size_t)b * 3 * HW + g;
    float r  = floorf(fminf(fmaxf(ib[0]    * 255.f, 0.f), 255.f));
    float gg = floorf(fminf(fmaxf(ib[HW]   * 255.f, 0.f), 255.f));
    float bb = floorf(fminf(fmaxf(ib[2*HW] * 255.f, 0.f), 255.f));
    Hu rg; rg.h = __floats2half2_rn(r, gg);
    Hu b0; b0.h = __floats2half2_rn(bb, 0.f);
    IQ2[p] = make_uint2(rg.u32, b0.u32);
}

// ---------------------------------------------------------------------------
// Init: U = -log(clip(softmax(logits),1e-5,1)) (f32); Q0 = softmax(-U) packed f16
__global__ __launch_bounds__(256) void k_init(const float* __restrict__ logits,
                                              float* __restrict__ U,
                                              unsigned int* __restrict__ Qp) {
    int p = blockIdx.x * 256 + threadIdx.x;
    int b = p >> 16, g = p & (HW - 1);
    const float* lp = logits + (size_t)b * C * HW + g;

    float v[C];
    float m = -1e30f;
#pragma unroll
    for (int c = 0; c < C; ++c) { v[c] = lp[c*HW]; m = fmaxf(m, v[c]); }
    float s = 0.f;
#pragma unroll
    for (int c = 0; c < C; ++c) { v[c] = __expf(v[c] - m); s += v[c]; }
    float inv = 1.f / s;

    float u[C];
    float m2 = -1e30f;
#pragma unroll
    for (int c = 0; c < C; ++c) {
        float sm = fminf(fmaxf(v[c] * inv, 1e-5f), 1.f);
        float uu = -__logf(sm);
        u[c] = uu;
        m2 = fmaxf(m2, -uu);
    }
    float s2 = 0.f;
    float q[C];
#pragma unroll
    for (int c = 0; c < C; ++c) { q[c] = __expf(-u[c] - m2); s2 += q[c]; }
    float inv2 = 1.f / s2;

    float* Up = U + (size_t)b * C * HW + g;
    unsigned int* Qb = Qp + (size_t)b * NP * HW + g;
#pragma unroll
    for (int c = 0; c < C; ++c) Up[c*HW] = u[c];
#pragma unroll
    for (int k = 0; k < NP; ++k) {
        float a = q[2*k] * inv2;
        float bb = (2*k + 1 < C) ? q[2*k + 1] * inv2 : 0.f;
        Hu x; x.h = __floats2half2_rn(a, bb);
        Qb[k*HW] = x.u32;
    }
}

// ---------------------------------------------------------------------------
// Gaussian horizontal pass over packed pairs (zero-padded), float4-chunked
__global__ __launch_bounds__(256) void k_gh(const unsigned int* __restrict__ Q,
                                            unsigned int* __restrict__ T,
                                            const float* __restrict__ kt) {
    __shared__ float kf[19];
    if (threadIdx.x < 19) kf[threadIdx.x] = kt[threadIdx.x];
    __syncthreads();
    __half2 kh[19];
#pragma unroll
    for (int j = 0; j < 19; ++j) kh[j] = __float2half2_rn(kf[j]);

    int e = (blockIdx.x * 256 + threadIdx.x) * 4;    // uint index, 4-aligned in x
    int x0 = e & (W - 1);
    const unsigned int* row = Q + (e - x0);

    U4 ch[7];
#pragma unroll
    for (int c2 = 0; c2 < 7; ++c2) {
        int xb = x0 - 12 + c2 * 4;
        if ((unsigned)xb < (unsigned)W) ch[c2].u = *(const uint4*)(row + xb);
        else ch[c2].u = make_uint4(0,0,0,0);
    }
    const __half2* v = (const __half2*)ch;           // v[0..27] = x0-12 .. x0+15

    U4 o;
#pragma unroll
    for (int i = 0; i < 4; ++i) {
        __half2 acc = __float2half2_rn(0.f);
#pragma unroll
        for (int j = 0; j < 19; ++j) acc = __hfma2(kh[j], v[i + 3 + j], acc);
        o.h[i] = acc;
    }
    *(uint4*)(T + e) = o.u;
}

// Gaussian vertical pass + message, 4-row register-blocked sliding window:
// MG = (conv - w0*Q)*(1/(1-w0))
__global__ __launch_bounds__(256) void k_gv(const unsigned int* __restrict__ T,
                                            const unsigned int* __restrict__ Q,
                                            unsigned int* __restrict__ MG,
                                            const float* __restrict__ kt) {
    __shared__ float kf[21];
    if (threadIdx.x < 21) kf[threadIdx.x] = kt[threadIdx.x];
    __syncthreads();
    __half2 kh[19];
#pragma unroll
    for (int j = 0; j < 19; ++j) kh[j] = __float2half2_rn(kf[j]);
    __half2 nw0  = __float2half2_rn(-kf[19]);
    __half2 inv1 = __float2half2_rn(1.f / kf[20]);

    int t = blockIdx.x * 256 + threadIdx.x;   // NB2/16 threads
    int xq = (t & 63) * 4;                    // col quad (uints)
    int y0 = ((t >> 6) & 63) * 4;             // 4-row group
    int pl = t >> 12;                         // plane 0..B*NP-1
    const unsigned int* base = T + (size_t)pl * HW;

    __half2 acc[4][4];
#pragma unroll
    for (int i = 0; i < 4; ++i)
#pragma unroll
        for (int q = 0; q < 4; ++q) acc[i][q] = __float2half2_rn(0.f);

#pragma unroll
    for (int j = 0; j < 22; ++j) {
        int yy = y0 + j - 9;
        if ((unsigned)yy < (unsigned)H) {
            U4 f; f.u = *(const uint4*)(base + yy * W + xq);
#pragma unroll
            for (int i = 0; i < 4; ++i) {
                int tap = j - i;
                if (tap >= 0 && tap <= 18) {
#pragma unroll
                    for (int q = 0; q < 4; ++q)
                        acc[i][q] = __hfma2(kh[tap], f.h[q], acc[i][q]);
                }
            }
        }
    }

#pragma unroll
    for (int i = 0; i < 4; ++i) {
        size_t e = (size_t)pl * HW + (y0 + i) * W + xq;
        U4 q; q.u = *(const uint4*)(Q + e);
        U4 o;
#pragma unroll
        for (int qd = 0; qd < 4; ++qd)
            o.h[qd] = __hmul2(__hfma2(nw0, q.h[qd], acc[i][qd]), inv1);
        *(uint4*)(MG + e) = o.u;
    }
}

// ---------------------------------------------------------------------------
// Bilateral message + mean-field update. 2 px per thread (rows r, r+1 share
// 12/14 neighbor rows -> each LDS tap feeds both outputs). 48 B/px LDS record:
// 3x uint4 = 21 Q pairs + (ch20,r),(g,b).
__global__ __launch_bounds__(256) void k_update(const unsigned int* __restrict__ Q,
                                                const float* __restrict__ U,
                                                const unsigned int* __restrict__ MG,
                                                const uint2* __restrict__ IQ2,
                                                unsigned int* __restrict__ Qn) {
    __shared__ uint4 LA[NSL];   // pairs 0..3   (ch 0..7)
    __shared__ uint4 LB[NSL];   // pairs 4..7   (ch 8..15)
    __shared__ uint4 LC[NSL];   // pair8, pair9, (ch20,r), (g,b)

    int blk = blockIdx.x;
    int b = blk >> 7;                 // 128 tiles per image (8y x 16x)
    int tile = blk & 127;
    int ty0 = (tile >> 4) * TSY;
    int tx0 = (tile & 15) * TSX;
    int tid = threadIdx.x;

    const unsigned int* Qb = Q + (size_t)b * NP * HW;
    const uint2* Ib = IQ2 + (size_t)b * HW;

    for (int s = tid; s < NSL; s += 256) {
        int ly = s / HX;
        int lx = s - ly * HX;
        int gy = ty0 + ly - R;
        int gx = tx0 + lx - R;
        bool in = ((unsigned)gy < (unsigned)H) && ((unsigned)gx < (unsigned)W);
        int g = gy * W + gx;
        unsigned int u[NP];
#pragma unroll
        for (int k = 0; k < NP; ++k) u[k] = in ? Qb[k*HW + g] : 0u;
        uint2 rgb = in ? Ib[g] : make_uint2(0u, 0u);
        LA[s] = make_uint4(u[0], u[1], u[2], u[3]);
        LB[s] = make_uint4(u[4], u[5], u[6], u[7]);
        unsigned int c2 = (u[10] & 0xffffu) | (rgb.x << 16);   // (ch20, r)
        unsigned int c3 = (rgb.x >> 16) | (rgb.y << 16);       // (g, b)
        LC[s] = make_uint4(u[8], u[9], c2, c3);
    }
    __syncthreads();

    int x = tid & 15;
    int ry = tid >> 4;                // 0..15 -> output rows 2ry, 2ry+1
    int r0 = 2 * ry;
    int cp0 = (r0 + R) * HX + x + R;  // LDS index of center0; center1 = cp0+HX

    float cr0, cg0, cb0, cr1, cg1, cb1;
    {
        U4 cc; cc.u = LC[cp0];
        Hu hz; hz.u32 = cc.u.z;  Hu hw2; hw2.u32 = cc.u.w;
        cr0 = __half2float(__high2half(hz.h));
        cg0 = __half2float(__low2half(hw2.h));
        cb0 = __half2float(__high2half(hw2.h));
        cc.u = LC[cp0 + HX];
        hz.u32 = cc.u.z;  hw2.u32 = cc.u.w;
        cr1 = __half2float(__high2half(hz.h));
        cg1 = __half2float(__low2half(hw2.h));
        cb1 = __half2float(__high2half(hw2.h));
    }

    float kx[13];
#pragma unroll
    for (int j = 0; j < 13; ++j)
        kx[j] = exp2f(-(float)((j - 6) * (j - 6)) * C2F);

    __half2 m0[NP], m1[NP];
#pragma unroll
    for (int k = 0; k < NP; ++k) { m0[k] = __float2half2_rn(0.f); m1[k] = m0[k]; }
    float ws0 = 0.f, ws1 = 0.f;

    for (int dyy = -R; dyy <= R + 1; ++dyy) {
        int lrow = cp0 + dyy * HX;
        float a0 = (dyy <= R) ? -(float)(dyy * dyy) * C2F : -INFINITY;
        int d1 = dyy - 1;
        float a1 = (d1 >= -R) ? -(float)(d1 * d1) * C2F : -INFINITY;
        bool z0 = (dyy == 0), z1 = (dyy == 1);
#pragma unroll
        for (int dx = -R; dx <= R; ++dx) {
            int p = lrow + dx;
            U4 A, Bq, Cq;
            A.u  = LA[p];
            Bq.u = LB[p];
            Cq.u = LC[p];
            Hu hz; hz.u32 = Cq.u.z;  Hu hw2; hw2.u32 = Cq.u.w;
            float pr = __half2float(__high2half(hz.h));
            float pg = __half2float(__low2half(hw2.h));
            float pb = __half2float(__high2half(hw2.h));
            float d0r = cr0 - pr, d0g = cg0 - pg, d0b = cb0 - pb;
            float d1r = cr1 - pr, d1g = cg1 - pg, d1b = cb1 - pb;
            float ss0 = fmaf(d0r, d0r, fmaf(d0g, d0g, d0b * d0b));
            float ss1 = fmaf(d1r, d1r, fmaf(d1g, d1g, d1b * d1b));
            float w0 = kx[dx + R] * exp2f(fmaf(ss0, -C2F, a0));
            float w1 = kx[dx + R] * exp2f(fmaf(ss1, -C2F, a1));
            if (dx == 0) { if (z0) w0 = 0.f; if (z1) w1 = 0.f; }
            ws0 += w0; ws1 += w1;
            __half2 wh0 = __float2half2_rn(w0);
            __half2 wh1 = __float2half2_rn(w1);
            m0[0] = __hfma2(wh0, A.h[0], m0[0]);   m1[0] = __hfma2(wh1, A.h[0], m1[0]);
            m0[1] = __hfma2(wh0, A.h[1], m0[1]);   m1[1] = __hfma2(wh1, A.h[1], m1[1]);
            m0[2] = __hfma2(wh0, A.h[2], m0[2]);   m1[2] = __hfma2(wh1, A.h[2], m1[2]);
            m0[3] = __hfma2(wh0, A.h[3], m0[3]);   m1[3] = __hfma2(wh1, A.h[3], m1[3]);
            m0[4] = __hfma2(wh0, Bq.h[0], m0[4]);  m1[4] = __hfma2(wh1, Bq.h[0], m1[4]);
            m0[5] = __hfma2(wh0, Bq.h[1], m0[5]);  m1[5] = __hfma2(wh1, Bq.h[1], m1[5]);
            m0[6] = __hfma2(wh0, Bq.h[2], m0[6]);  m1[6] = __hfma2(wh1, Bq.h[2], m1[6]);
            m0[7] = __hfma2(wh0, Bq.h[3], m0[7]);  m1[7] = __hfma2(wh1, Bq.h[3], m1[7]);
            m0[8] = __hfma2(wh0, Cq.h[0], m0[8]);  m1[8] = __hfma2(wh1, Cq.h[0], m1[8]);
            m0[9] = __hfma2(wh0, Cq.h[1], m0[9]);  m1[9] = __hfma2(wh1, Cq.h[1], m1[9]);
            m0[10] = __hfma2(wh0, Cq.h[2], m0[10]); m1[10] = __hfma2(wh1, Cq.h[2], m1[10]);
        }
    }

    // Epilogue: softmax update for both pixels
    const float* Ub = U + (size_t)b * C * HW;
    const unsigned int* Mb = MG + (size_t)b * NP * HW;
    unsigned int* Qo = Qn + (size_t)b * NP * HW;

#pragma unroll
    for (int px = 0; px < 2; ++px) {
        const __half2* m = px ? m1 : m0;
        float inv = 1.f / ((px ? ws1 : ws0) + 1e-8f);
        int g = (ty0 + r0 + px) * W + (tx0 + x);
        float sv[C];
        float mm = -1e30f;
#pragma unroll
        for (int k = 0; k < NP; ++k) {
            float2 mf = __half22float2(m[k]);
            Hu mgu; mgu.u32 = Mb[k*HW + g];
            float2 mgf = __half22float2(mgu.h);
            int c0 = 2 * k;
            float v0 = -Ub[c0*HW + g] + 3.f * mgf.x + 10.f * (mf.x * inv);
            sv[c0] = v0; mm = fmaxf(mm, v0);
            if (c0 + 1 < C) {
                float v1 = -Ub[(c0+1)*HW + g] + 3.f * mgf.y + 10.f * (mf.y * inv);
                sv[c0+1] = v1; mm = fmaxf(mm, v1);
            }
        }
        float s = 0.f;
#pragma unroll
        for (int c = 0; c < C; ++c) { sv[c] = __expf(sv[c] - mm); s += sv[c]; }
        float is = 1.f / s;
#pragma unroll
        for (int k = 0; k < NP; ++k) {
            float a = sv[2*k] * is;
            float bb = (2*k + 1 < C) ? sv[2*k + 1] * is : 0.f;
            Hu xh; xh.h = __floats2half2_rn(a, bb);
            Qo[k*HW + g] = xh.u32;
        }
    }
}

// ---------------------------------------------------------------------------
// Loss: per-pixel NLL of log_softmax(log(Q+1e-8)) at label; block partial sums
__global__ __launch_bounds__(256) void k_loss(const unsigned int* __restrict__ Q,
                                              const int* __restrict__ labels,
                                              float* __restrict__ part) {
    int p = blockIdx.x * 256 + threadIdx.x;
    int b = p >> 16, g = p & (HW - 1);
    const unsigned int* Qb = Q + (size_t)b * NP * HW + g;
    int lab = labels[p];
    float s = 0.f, ql = 1e-8f;
#pragma unroll
    for (int k = 0; k < NP; ++k) {
        Hu x; x.u32 = Qb[k*HW];
        float2 f = __half22float2(x.h);
        int c0 = 2 * k;
        float q0 = f.x + 1e-8f;
        s += q0;
        if (c0 == lab) ql = q0;
        if (c0 + 1 < C) {
            float q1 = f.y + 1e-8f;
            s += q1;
            if (c0 + 1 == lab) ql = q1;
        }
    }
    float nll = __logf(s) - __logf(ql);
#pragma unroll
    for (int off = 32; off > 0; off >>= 1) nll += __shfl_down(nll, off);
    __shared__ float red[4];
    int lane = threadIdx.x & 63, wv = threadIdx.x >> 6;
    if (lane == 0) red[wv] = nll;
    __syncthreads();
    if (threadIdx.x == 0) part[blockIdx.x] = red[0] + red[1] + red[2] + red[3];
}

__global__ __launch_bounds__(256) void k_final(const float* __restrict__ part,
                                               float* __restrict__ out) {
    int tid = threadIdx.x;
    float s = part[tid] + part[tid + 256] + part[tid + 512] + part[tid + 768];
#pragma unroll
    for (int off = 32; off > 0; off >>= 1) s += __shfl_down(s, off);
    __shared__ float red[4];
    int lane = tid & 63, wv = tid >> 6;
    if (lane == 0) red[wv] = s;
    __syncthreads();
    if (tid == 0) out[0] = (red[0] + red[1] + red[2] + red[3]) / (float)NPIX;
}

// ---------------------------------------------------------------------------
extern "C" void kernel_launch(void* const* d_in, const int* in_sizes, int n_in,
                              void* d_out, int out_size, void* d_ws, size_t ws_size,
                              hipStream_t stream) {
    const float* logits = (const float*)d_in[0];
    const float* images = (const float*)d_in[1];
    const int*   labels = (const int*)d_in[2];
    float* out = (float*)d_out;

    float* ws = (float*)d_ws;
    float*        Ubuf = ws;                                    // NB f32
    unsigned int* QA   = (unsigned int*)(ws + (size_t)NB);      // NB2
    unsigned int* QB   = QA + (size_t)NB2;                      // NB2 (+ gh tmp alias)
    unsigned int* Mpk  = QB + (size_t)NB2;                      // NB2
    uint2*        IQ2  = (uint2*)(Mpk + (size_t)NB2);           // NPIX uint2
    float*        KT   = (float*)(IQ2 + (size_t)NPIX);          // 64 f32
    float*        PART = KT + 64;                               // 1024 f32

    k_ktab<<<1, 64, 0, stream>>>(KT);
    k_prep<<<NPIX/256, 256, 0, stream>>>(images, IQ2);
    k_init<<<NPIX/256, 256, 0, stream>>>(logits, Ubuf, QA);

    unsigned int* cur = QA;
    unsigned int* oth = QB;
    for (int it = 0; it < 5; ++it) {
        // gh tmp lives in the (currently dead) other Q buffer
        k_gh<<<NB2/1024, 256, 0, stream>>>(cur, oth, KT);
        k_gv<<<NB2/4096, 256, 0, stream>>>(oth, cur, Mpk, KT);
        k_update<<<B*128, 256, 0, stream>>>(cur, Ubuf, Mpk, IQ2, oth);
        unsigned int* t = cur; cur = oth; oth = t;
    }

    k_loss<<<NPIX/256, 256, 0, stream>>>(cur, labels, PART);
    k_final<<<1, 256, 0, stream>>>(PART, out);
    (void)in_sizes; (void)n_in; (void)out_size; (void)ws_size;
}

// Round 6
// 350.737 us; speedup vs baseline: 2.9266x; 1.1331x over previous
//
#include <hip/hip_runtime.h>
#include <hip/hip_fp16.h>
#include <math.h>

// Problem constants
#define B 4
#define C 21
#define NP 11               // f16 channel pairs (ch 2k, 2k+1; pair 10 high = pad)
#define H 256
#define W 256
#define HW (H*W)            // 65536
#define NPIX (B*HW)         // 262144
#define NB2 (B*NP*HW)       // 2883584 packed uint elements

#define TSX 16              // update tile x
#define TSY 32              // update tile y (2 rows per thread)
#define R 6                 // bilateral radius
#define HX 28               // real halo width
#define HXP 29              // padded LDS row stride (breaks 128B phase alignment)
#define HY (TSY + 2*R)      // 44
#define NS (HX*HY)          // 1232 real entries
#define NSP (HXP*HY)        // 1276 padded entries

#define C2F ((float)(1.4426950408889634 / 338.0))   // log2(e)/338

// Gaussian-fused kernel geometry
#define GOY 64
#define GTR (GOY + 18)      // 82 T rows
#define GTS 17              // padded quad stride (17*16B = 272B -> 4-bank skew/row)

union U4 { uint4 u; __half2 h[4]; };
union Hu { unsigned int u32; __half2 h; };

// ---------------------------------------------------------------------------
// Gaussian taps: kt[0..18] normalized (sigma=3), kt[19]=w0, kt[20]=1-w0
__global__ void k_ktab(float* __restrict__ kt) {
    if (threadIdx.x == 0) {
        float e[19]; float s = 0.f;
        for (int i = 0; i < 19; ++i) {
            double d = (double)(i - 9);
            e[i] = (float)exp(-(d*d) / 18.0);
            s += e[i];
        }
        for (int i = 0; i < 19; ++i) kt[i] = e[i] / s;
        float k9 = e[9] / s;
        kt[19] = k9 * k9;
        kt[20] = 1.f - k9 * k9;
    }
}

// ---------------------------------------------------------------------------
// Pre-quantize image once into packed halves: (r,g),(b,0) — integers 0..255
__global__ __launch_bounds__(256) void k_prep(const float* __restrict__ img,
                                              uint2* __restrict__ IQ2) {
    int p = blockIdx.x * 256 + threadIdx.x;
    int b = p >> 16, g = p & (HW - 1);
    const float* ib = img + (size_t)b * 3 * HW + g;
    float r  = floorf(fminf(fmaxf(ib[0]    * 255.f, 0.f), 255.f));
    float gg = floorf(fminf(fmaxf(ib[HW]   * 255.f, 0.f), 255.f));
    float bb = floorf(fminf(fmaxf(ib[2*HW] * 255.f, 0.f), 255.f));
    Hu rg; rg.h = __floats2half2_rn(r, gg);
    Hu b0; b0.h = __floats2half2_rn(bb, 0.f);
    IQ2[p] = make_uint2(rg.u32, b0.u32);
}

// ---------------------------------------------------------------------------
// Init: U = -log(clip(softmax(logits),1e-5,1)) packed f16; Q0 = softmax(-U) packed f16
__global__ __launch_bounds__(256) void k_init(const float* __restrict__ logits,
                                              unsigned int* __restrict__ Upk,
                                              unsigned int* __restrict__ Qp) {
    int p = blockIdx.x * 256 + threadIdx.x;
    int b = p >> 16, g = p & (HW - 1);
    const float* lp = logits + (size_t)b * C * HW + g;

    float v[C];
    float m = -1e30f;
#pragma unroll
    for (int c = 0; c < C; ++c) { v[c] = lp[c*HW]; m = fmaxf(m, v[c]); }
    float s = 0.f;
#pragma unroll
    for (int c = 0; c < C; ++c) { v[c] = __expf(v[c] - m); s += v[c]; }
    float inv = 1.f / s;

    float u[C];
    float m2 = -1e30f;
#pragma unroll
    for (int c = 0; c < C; ++c) {
        float sm = fminf(fmaxf(v[c] * inv, 1e-5f), 1.f);
        float uu = -__logf(sm);
        u[c] = uu;
        m2 = fmaxf(m2, -uu);
    }
    float s2 = 0.f;
    float q[C];
#pragma unroll
    for (int c = 0; c < C; ++c) { q[c] = __expf(-u[c] - m2); s2 += q[c]; }
    float inv2 = 1.f / s2;

    unsigned int* Ub = Upk + (size_t)b * NP * HW + g;
    unsigned int* Qb = Qp + (size_t)b * NP * HW + g;
#pragma unroll
    for (int k = 0; k < NP; ++k) {
        float ua = u[2*k];
        float ub = (2*k + 1 < C) ? u[2*k + 1] : 0.f;
        Hu xu; xu.h = __floats2half2_rn(ua, ub);
        Ub[k*HW] = xu.u32;
        float qa = q[2*k] * inv2;
        float qb = (2*k + 1 < C) ? q[2*k + 1] * inv2 : 0.f;
        Hu xq; xq.h = __floats2half2_rn(qa, qb);
        Qb[k*HW] = xq.u32;
    }
}

// ---------------------------------------------------------------------------
// Fused separable Gaussian (horizontal into LDS, vertical from LDS) + message:
// MG = (conv - w0*Q)*(1/(1-w0)). One block = one plane x 64-row x 64-col tile.
__global__ __launch_bounds__(256) void k_gauss(const unsigned int* __restrict__ Q,
                                               unsigned int* __restrict__ MG,
                                               const float* __restrict__ kt) {
    __shared__ uint4 T[GTR * GTS];   // 82*17*16 = 22304 B
    __shared__ float kf[21];

    int tid = threadIdx.x;
    if (tid < 21) kf[tid] = kt[tid];
    __syncthreads();

    __half2 kh[19];
#pragma unroll
    for (int j = 0; j < 19; ++j) kh[j] = __float2half2_rn(kf[j]);

    int blk = blockIdx.x;
    int pl  = blk >> 4;          // plane 0..B*NP-1
    int sub = blk & 15;
    int y0 = (sub >> 2) * GOY;
    int x0 = (sub & 3) * 64;
    const unsigned int* base = Q + (size_t)pl * HW;

    // Stage T = horizontal conv (zero-padded x), rows y0-9 .. y0+72
    for (int s = tid; s < GTR * 16; s += 256) {
        int row = s >> 4;
        int q   = s & 15;
        int yy = y0 + row - 9;
        U4 o;
        o.u = make_uint4(0u, 0u, 0u, 0u);
        if ((unsigned)yy < (unsigned)H) {
            int xb = x0 + q * 4;
            const unsigned int* rp = base + yy * W;
            U4 ch[7];
#pragma unroll
            for (int c2 = 0; c2 < 7; ++c2) {
                int xq = xb - 12 + c2 * 4;
                if ((unsigned)xq < (unsigned)W) ch[c2].u = *(const uint4*)(rp + xq);
                else ch[c2].u = make_uint4(0u, 0u, 0u, 0u);
            }
            const __half2* v = (const __half2*)ch;
#pragma unroll
            for (int i = 0; i < 4; ++i) {
                __half2 acc = __float2half2_rn(0.f);
#pragma unroll
                for (int j = 0; j < 19; ++j) acc = __hfma2(kh[j], v[i + 3 + j], acc);
                o.h[i] = acc;
            }
        }
        T[row * GTS + q] = o.u;
    }
    __syncthreads();

    // Vertical pass: 4 rows x 4-uint quad per thread, sliding taps
    __half2 nw0  = __float2half2_rn(-kf[19]);
    __half2 inv1 = __float2half2_rn(1.f / kf[20]);
    int q  = tid & 15;
    int rg = tid >> 4;           // 0..15
    int r0 = rg * 4;

    __half2 acc[4][4];
#pragma unroll
    for (int i = 0; i < 4; ++i)
#pragma unroll
        for (int qd = 0; qd < 4; ++qd) acc[i][qd] = __float2half2_rn(0.f);

#pragma unroll
    for (int j = 0; j < 22; ++j) {
        U4 f; f.u = T[(r0 + j) * GTS + q];
#pragma unroll
        for (int i = 0; i < 4; ++i) {
            int tap = j - i;
            if (tap >= 0 && tap <= 18) {
#pragma unroll
                for (int qd = 0; qd < 4; ++qd)
                    acc[i][qd] = __hfma2(kh[tap], f.h[qd], acc[i][qd]);
            }
        }
    }

#pragma unroll
    for (int i = 0; i < 4; ++i) {
        size_t e = (size_t)pl * HW + (y0 + r0 + i) * W + x0 + q * 4;
        U4 qq; qq.u = *(const uint4*)(Q + e);
        U4 o;
#pragma unroll
        for (int qd = 0; qd < 4; ++qd)
            o.h[qd] = __hmul2(__hfma2(nw0, qq.h[qd], acc[i][qd]), inv1);
        *(uint4*)(MG + e) = o.u;
    }
}

// ---------------------------------------------------------------------------
// Bilateral message + mean-field update (2 px/thread in y; padded LDS stride).
// Last iteration (labels != null): compute NLL partial sums instead of writing Q.
__global__ __launch_bounds__(256) void k_update(const unsigned int* __restrict__ Q,
                                                const unsigned int* __restrict__ Upk,
                                                const unsigned int* __restrict__ MG,
                                                const uint2* __restrict__ IQ2,
                                                unsigned int* __restrict__ Qn,
                                                const int* __restrict__ labels,
                                                float* __restrict__ part) {
    __shared__ uint4 LA[NSP];   // pairs 0..3   (ch 0..7)
    __shared__ uint4 LB[NSP];   // pairs 4..7   (ch 8..15)
    __shared__ uint4 LC[NSP];   // pair8, pair9, (ch20,r), (g,b)
    __shared__ float red[4];

    int blk = blockIdx.x;
    int b = blk >> 7;                 // 128 tiles per image (8y x 16x)
    int tile = blk & 127;
    int ty0 = (tile >> 4) * TSY;
    int tx0 = (tile & 15) * TSX;
    int tid = threadIdx.x;

    const unsigned int* Qb = Q + (size_t)b * NP * HW;
    const uint2* Ib = IQ2 + (size_t)b * HW;

    for (int s = tid; s < NS; s += 256) {
        int ly = s / HX;
        int lx = s - ly * HX;
        int p  = ly * HXP + lx;
        int gy = ty0 + ly - R;
        int gx = tx0 + lx - R;
        bool in = ((unsigned)gy < (unsigned)H) && ((unsigned)gx < (unsigned)W);
        int g = gy * W + gx;
        unsigned int u[NP];
#pragma unroll
        for (int k = 0; k < NP; ++k) u[k] = in ? Qb[k*HW + g] : 0u;
        uint2 rgb = in ? Ib[g] : make_uint2(0u, 0u);
        LA[p] = make_uint4(u[0], u[1], u[2], u[3]);
        LB[p] = make_uint4(u[4], u[5], u[6], u[7]);
        unsigned int c2 = (u[10] & 0xffffu) | (rgb.x << 16);   // (ch20, r)
        unsigned int c3 = (rgb.x >> 16) | (rgb.y << 16);       // (g, b)
        LC[p] = make_uint4(u[8], u[9], c2, c3);
    }
    __syncthreads();

    int x = tid & 15;
    int ry = tid >> 4;                // 0..15 -> output rows 2ry, 2ry+1
    int r0 = 2 * ry;
    int cp0 = (r0 + R) * HXP + x + R;

    float cr0, cg0, cb0, cr1, cg1, cb1;
    {
        U4 cc; cc.u = LC[cp0];
        Hu hz; hz.u32 = cc.u.z;  Hu hw2; hw2.u32 = cc.u.w;
        cr0 = __half2float(__high2half(hz.h));
        cg0 = __half2float(__low2half(hw2.h));
        cb0 = __half2float(__high2half(hw2.h));
        cc.u = LC[cp0 + HXP];
        hz.u32 = cc.u.z;  hw2.u32 = cc.u.w;
        cr1 = __half2float(__high2half(hz.h));
        cg1 = __half2float(__low2half(hw2.h));
        cb1 = __half2float(__high2half(hw2.h));
    }

    float kx[13];
#pragma unroll
    for (int j = 0; j < 13; ++j)
        kx[j] = exp2f(-(float)((j - 6) * (j - 6)) * C2F);

    __half2 m0[NP], m1[NP];
#pragma unroll
    for (int k = 0; k < NP; ++k) { m0[k] = __float2half2_rn(0.f); m1[k] = m0[k]; }
    float ws0 = 0.f, ws1 = 0.f;

    for (int dyy = -R; dyy <= R + 1; ++dyy) {
        int lrow = cp0 + dyy * HXP;
        float a0 = (dyy <= R) ? -(float)(dyy * dyy) * C2F : -INFINITY;
        int d1 = dyy - 1;
        float a1 = (d1 >= -R) ? -(float)(d1 * d1) * C2F : -INFINITY;
        bool z0 = (dyy == 0), z1 = (dyy == 1);
#pragma unroll
        for (int dx = -R; dx <= R; ++dx) {
            int p = lrow + dx;
            U4 A, Bq, Cq;
            A.u  = LA[p];
            Bq.u = LB[p];
            Cq.u = LC[p];
            Hu hz; hz.u32 = Cq.u.z;  Hu hw2; hw2.u32 = Cq.u.w;
            float pr = __half2float(__high2half(hz.h));
            float pg = __half2float(__low2half(hw2.h));
            float pb = __half2float(__high2half(hw2.h));
            float d0r = cr0 - pr, d0g = cg0 - pg, d0b = cb0 - pb;
            float d1r = cr1 - pr, d1g = cg1 - pg, d1b = cb1 - pb;
            float ss0 = fmaf(d0r, d0r, fmaf(d0g, d0g, d0b * d0b));
            float ss1 = fmaf(d1r, d1r, fmaf(d1g, d1g, d1b * d1b));
            float w0 = kx[dx + R] * exp2f(fmaf(ss0, -C2F, a0));
            float w1 = kx[dx + R] * exp2f(fmaf(ss1, -C2F, a1));
            if (dx == 0) { if (z0) w0 = 0.f; if (z1) w1 = 0.f; }
            ws0 += w0; ws1 += w1;
            __half2 wh0 = __float2half2_rn(w0);
            __half2 wh1 = __float2half2_rn(w1);
            m0[0] = __hfma2(wh0, A.h[0], m0[0]);   m1[0] = __hfma2(wh1, A.h[0], m1[0]);
            m0[1] = __hfma2(wh0, A.h[1], m0[1]);   m1[1] = __hfma2(wh1, A.h[1], m1[1]);
            m0[2] = __hfma2(wh0, A.h[2], m0[2]);   m1[2] = __hfma2(wh1, A.h[2], m1[2]);
            m0[3] = __hfma2(wh0, A.h[3], m0[3]);   m1[3] = __hfma2(wh1, A.h[3], m1[3]);
            m0[4] = __hfma2(wh0, Bq.h[0], m0[4]);  m1[4] = __hfma2(wh1, Bq.h[0], m1[4]);
            m0[5] = __hfma2(wh0, Bq.h[1], m0[5]);  m1[5] = __hfma2(wh1, Bq.h[1], m1[5]);
            m0[6] = __hfma2(wh0, Bq.h[2], m0[6]);  m1[6] = __hfma2(wh1, Bq.h[2], m1[6]);
            m0[7] = __hfma2(wh0, Bq.h[3], m0[7]);  m1[7] = __hfma2(wh1, Bq.h[3], m1[7]);
            m0[8] = __hfma2(wh0, Cq.h[0], m0[8]);  m1[8] = __hfma2(wh1, Cq.h[0], m1[8]);
            m0[9] = __hfma2(wh0, Cq.h[1], m0[9]);  m1[9] = __hfma2(wh1, Cq.h[1], m1[9]);
            m0[10] = __hfma2(wh0, Cq.h[2], m0[10]); m1[10] = __hfma2(wh1, Cq.h[2], m1[10]);
        }
    }

    // Epilogue: softmax update (write Q) or NLL (last iteration)
    const unsigned int* Ub = Upk + (size_t)b * NP * HW;
    const unsigned int* Mb = MG + (size_t)b * NP * HW;
    unsigned int* Qo = Qn + (size_t)b * NP * HW;

    float nll = 0.f;
#pragma unroll
    for (int px = 0; px < 2; ++px) {
        const __half2* m = px ? m1 : m0;
        float inv = 1.f / ((px ? ws1 : ws0) + 1e-8f);
        int g = (ty0 + r0 + px) * W + (tx0 + x);
        float sv[C];
        float mm = -1e30f;
#pragma unroll
        for (int k = 0; k < NP; ++k) {
            float2 mf = __half22float2(m[k]);
            Hu mgu; mgu.u32 = Mb[k*HW + g];
            float2 mgf = __half22float2(mgu.h);
            Hu uu; uu.u32 = Ub[k*HW + g];
            float2 uf = __half22float2(uu.h);
            int c0 = 2 * k;
            float v0 = -uf.x + 3.f * mgf.x + 10.f * (mf.x * inv);
            sv[c0] = v0; mm = fmaxf(mm, v0);
            if (c0 + 1 < C) {
                float v1 = -uf.y + 3.f * mgf.y + 10.f * (mf.y * inv);
                sv[c0+1] = v1; mm = fmaxf(mm, v1);
            }
        }
        float s = 0.f;
#pragma unroll
        for (int c = 0; c < C; ++c) { sv[c] = __expf(sv[c] - mm); s += sv[c]; }
        if (labels) {
            int lab = labels[(size_t)b * HW + g];
            float qsum = 0.f, ql = 1e-8f;
#pragma unroll
            for (int c = 0; c < C; ++c) {
                float qc = sv[c] / s + 1e-8f;
                qsum += qc;
                if (c == lab) ql = qc;
            }
            nll += __logf(qsum) - __logf(ql);
        } else {
            float is = 1.f / s;
#pragma unroll
            for (int k = 0; k < NP; ++k) {
                float a = sv[2*k] * is;
                float bb = (2*k + 1 < C) ? sv[2*k + 1] * is : 0.f;
                Hu xh; xh.h = __floats2half2_rn(a, bb);
                Qo[k*HW + g] = xh.u32;
            }
        }
    }

    if (labels) {
#pragma unroll
        for (int off = 32; off > 0; off >>= 1) nll += __shfl_down(nll, off);
        int lane = tid & 63, wv = tid >> 6;
        if (lane == 0) red[wv] = nll;
        __syncthreads();
        if (tid == 0) part[blk] = red[0] + red[1] + red[2] + red[3];
    }
}

// ---------------------------------------------------------------------------
__global__ __launch_bounds__(256) void k_final(const float* __restrict__ part,
                                               float* __restrict__ out) {
    int tid = threadIdx.x;
    float s = part[tid] + part[tid + 256];
#pragma unroll
    for (int off = 32; off > 0; off >>= 1) s += __shfl_down(s, off);
    __shared__ float red[4];
    int lane = tid & 63, wv = tid >> 6;
    if (lane == 0) red[wv] = s;
    __syncthreads();
    if (tid == 0) out[0] = (red[0] + red[1] + red[2] + red[3]) / (float)NPIX;
}

// ---------------------------------------------------------------------------
extern "C" void kernel_launch(void* const* d_in, const int* in_sizes, int n_in,
                              void* d_out, int out_size, void* d_ws, size_t ws_size,
                              hipStream_t stream) {
    const float* logits = (const float*)d_in[0];
    const float* images = (const float*)d_in[1];
    const int*   labels = (const int*)d_in[2];
    float* out = (float*)d_out;

    unsigned int* ws = (unsigned int*)d_ws;
    unsigned int* Upk = ws;                     // NB2
    unsigned int* QA  = ws +   (size_t)NB2;     // NB2
    unsigned int* QB  = ws + 2*(size_t)NB2;     // NB2
    unsigned int* Mpk = ws + 3*(size_t)NB2;     // NB2
    uint2*        IQ2 = (uint2*)(ws + 4*(size_t)NB2);    // NPIX uint2
    float*        KT  = (float*)(IQ2 + (size_t)NPIX);    // 64 f32
    float*        PART = KT + 64;                        // 512 f32

    k_ktab<<<1, 64, 0, stream>>>(KT);
    k_prep<<<NPIX/256, 256, 0, stream>>>(images, IQ2);
    k_init<<<NPIX/256, 256, 0, stream>>>(logits, Upk, QA);

    unsigned int* cur = QA;
    unsigned int* oth = QB;
    for (int it = 0; it < 5; ++it) {
        k_gauss<<<B*NP*16, 256, 0, stream>>>(cur, Mpk, KT);
        k_update<<<B*128, 256, 0, stream>>>(cur, Upk, Mpk, IQ2, oth,
                                            (it == 4) ? labels : nullptr, PART);
        unsigned int* t = cur; cur = oth; oth = t;
    }

    k_final<<<1, 256, 0, stream>>>(PART, out);
    (void)in_sizes; (void)n_in; (void)out_size; (void)ws_size;
}

// Round 7
// 334.718 us; speedup vs baseline: 3.0666x; 1.0479x over previous
//
#include <hip/hip_runtime.h>
#include <hip/hip_fp16.h>
#include <math.h>

// Problem constants
#define B 4
#define C 21
#define NP 11               // f16 channel pairs (ch 2k, 2k+1; pair 10 high = pad)
#define H 256
#define W 256
#define HW (H*W)            // 65536
#define NPIX (B*HW)         // 262144
#define NB2 (B*NP*HW)       // 2883584 packed uint elements

#define TSX 16              // update tile x
#define TSY 32              // update tile y (2 rows per thread)
#define R 6                 // bilateral radius
#define HX 28               // halo width
#define HXP 29              // padded LDS row stride
#define HY (TSY + 2*R)      // 44
#define NS (HX*HY)          // 1232 real entries
#define NSP (HXP*HY)        // 1276 padded entries

#define C2F ((float)(1.4426950408889634 / 338.0))   // log2(e)/338

// Gaussian-fused kernel geometry
#define GOY 64
#define GTR (GOY + 18)      // 82 T rows
#define GTS 17              // padded quad stride

union U4 { uint4 u; __half2 h[4]; };
union Hu { unsigned int u32; __half2 h; };

__device__ __forceinline__ float fexp2(float x) {
    float r;
    asm("v_exp_f32 %0, %1" : "=v"(r) : "v"(x));
    return r;
}

// ---------------------------------------------------------------------------
// Gaussian taps: kt[0..18] normalized (sigma=3), kt[19]=w0, kt[20]=1-w0
__global__ void k_ktab(float* __restrict__ kt) {
    if (threadIdx.x == 0) {
        float e[19]; float s = 0.f;
        for (int i = 0; i < 19; ++i) {
            double d = (double)(i - 9);
            e[i] = (float)exp(-(d*d) / 18.0);
            s += e[i];
        }
        for (int i = 0; i < 19; ++i) kt[i] = e[i] / s;
        float k9 = e[9] / s;
        kt[19] = k9 * k9;
        kt[20] = 1.f - k9 * k9;
    }
}

// ---------------------------------------------------------------------------
// Pre-quantize image once into packed halves: (r,g),(b,0) — integers 0..255
__global__ __launch_bounds__(256) void k_prep(const float* __restrict__ img,
                                              uint2* __restrict__ IQ2) {
    int p = blockIdx.x * 256 + threadIdx.x;
    int b = p >> 16, g = p & (HW - 1);
    const float* ib = img + (size_t)b * 3 * HW + g;
    float r  = floorf(fminf(fmaxf(ib[0]    * 255.f, 0.f), 255.f));
    float gg = floorf(fminf(fmaxf(ib[HW]   * 255.f, 0.f), 255.f));
    float bb = floorf(fminf(fmaxf(ib[2*HW] * 255.f, 0.f), 255.f));
    Hu rg; rg.h = __floats2half2_rn(r, gg);
    Hu b0; b0.h = __floats2half2_rn(bb, 0.f);
    IQ2[p] = make_uint2(rg.u32, b0.u32);
}

// ---------------------------------------------------------------------------
// Init: U = -log(clip(softmax(logits),1e-5,1)) packed f16; Q0 = softmax(-U) packed f16
__global__ __launch_bounds__(256) void k_init(const float* __restrict__ logits,
                                              unsigned int* __restrict__ Upk,
                                              unsigned int* __restrict__ Qp) {
    int p = blockIdx.x * 256 + threadIdx.x;
    int b = p >> 16, g = p & (HW - 1);
    const float* lp = logits + (size_t)b * C * HW + g;

    float v[C];
    float m = -1e30f;
#pragma unroll
    for (int c = 0; c < C; ++c) { v[c] = lp[c*HW]; m = fmaxf(m, v[c]); }
    float s = 0.f;
#pragma unroll
    for (int c = 0; c < C; ++c) { v[c] = __expf(v[c] - m); s += v[c]; }
    float inv = 1.f / s;

    float u[C];
    float m2 = -1e30f;
#pragma unroll
    for (int c = 0; c < C; ++c) {
        float sm = fminf(fmaxf(v[c] * inv, 1e-5f), 1.f);
        float uu = -__logf(sm);
        u[c] = uu;
        m2 = fmaxf(m2, -uu);
    }
    float s2 = 0.f;
    float q[C];
#pragma unroll
    for (int c = 0; c < C; ++c) { q[c] = __expf(-u[c] - m2); s2 += q[c]; }
    float inv2 = 1.f / s2;

    unsigned int* Ub = Upk + (size_t)b * NP * HW + g;
    unsigned int* Qb = Qp + (size_t)b * NP * HW + g;
#pragma unroll
    for (int k = 0; k < NP; ++k) {
        float ua = u[2*k];
        float ub = (2*k + 1 < C) ? u[2*k + 1] : 0.f;
        Hu xu; xu.h = __floats2half2_rn(ua, ub);
        Ub[k*HW] = xu.u32;
        float qa = q[2*k] * inv2;
        float qb = (2*k + 1 < C) ? q[2*k + 1] * inv2 : 0.f;
        Hu xq; xq.h = __floats2half2_rn(qa, qb);
        Qb[k*HW] = xq.u32;
    }
}

// ---------------------------------------------------------------------------
// Fused separable Gaussian + message: MG = (conv - w0*Q)*(1/(1-w0)).
__global__ __launch_bounds__(256) void k_gauss(const unsigned int* __restrict__ Q,
                                               unsigned int* __restrict__ MG,
                                               const float* __restrict__ kt) {
    __shared__ uint4 T[GTR * GTS];
    __shared__ float kf[21];

    int tid = threadIdx.x;
    if (tid < 21) kf[tid] = kt[tid];
    __syncthreads();

    __half2 kh[19];
#pragma unroll
    for (int j = 0; j < 19; ++j) kh[j] = __float2half2_rn(kf[j]);

    int blk = blockIdx.x;
    int pl  = blk >> 4;
    int sub = blk & 15;
    int y0 = (sub >> 2) * GOY;
    int x0 = (sub & 3) * 64;
    const unsigned int* base = Q + (size_t)pl * HW;

    for (int s = tid; s < GTR * 16; s += 256) {
        int row = s >> 4;
        int q   = s & 15;
        int yy = y0 + row - 9;
        U4 o;
        o.u = make_uint4(0u, 0u, 0u, 0u);
        if ((unsigned)yy < (unsigned)H) {
            int xb = x0 + q * 4;
            const unsigned int* rp = base + yy * W;
            U4 ch[7];
#pragma unroll
            for (int c2 = 0; c2 < 7; ++c2) {
                int xq = xb - 12 + c2 * 4;
                if ((unsigned)xq < (unsigned)W) ch[c2].u = *(const uint4*)(rp + xq);
                else ch[c2].u = make_uint4(0u, 0u, 0u, 0u);
            }
            const __half2* v = (const __half2*)ch;
#pragma unroll
            for (int i = 0; i < 4; ++i) {
                __half2 acc = __float2half2_rn(0.f);
#pragma unroll
                for (int j = 0; j < 19; ++j) acc = __hfma2(kh[j], v[i + 3 + j], acc);
                o.h[i] = acc;
            }
        }
        T[row * GTS + q] = o.u;
    }
    __syncthreads();

    __half2 nw0  = __float2half2_rn(-kf[19]);
    __half2 inv1 = __float2half2_rn(1.f / kf[20]);
    int q  = tid & 15;
    int rg = tid >> 4;
    int r0 = rg * 4;

    __half2 acc[4][4];
#pragma unroll
    for (int i = 0; i < 4; ++i)
#pragma unroll
        for (int qd = 0; qd < 4; ++qd) acc[i][qd] = __float2half2_rn(0.f);

#pragma unroll
    for (int j = 0; j < 22; ++j) {
        U4 f; f.u = T[(r0 + j) * GTS + q];
#pragma unroll
        for (int i = 0; i < 4; ++i) {
            int tap = j - i;
            if (tap >= 0 && tap <= 18) {
#pragma unroll
                for (int qd = 0; qd < 4; ++qd)
                    acc[i][qd] = __hfma2(kh[tap], f.h[qd], acc[i][qd]);
            }
        }
    }

#pragma unroll
    for (int i = 0; i < 4; ++i) {
        size_t e = (size_t)pl * HW + (y0 + r0 + i) * W + x0 + q * 4;
        U4 qq; qq.u = *(const uint4*)(Q + e);
        U4 o;
#pragma unroll
        for (int qd = 0; qd < 4; ++qd)
            o.h[qd] = __hmul2(__hfma2(nw0, qq.h[qd], acc[i][qd]), inv1);
        *(uint4*)(MG + e) = o.u;
    }
}

// ---------------------------------------------------------------------------
// Bilateral message + mean-field update (2 px/thread in y).
// Native v_exp_f32, log2-folded spatial args, ss1-delta, epilogue prefetch.
__global__ __launch_bounds__(256) void k_update(const unsigned int* __restrict__ Q,
                                                const unsigned int* __restrict__ Upk,
                                                const unsigned int* __restrict__ MG,
                                                const uint2* __restrict__ IQ2,
                                                unsigned int* __restrict__ Qn,
                                                const int* __restrict__ labels,
                                                float* __restrict__ part) {
    __shared__ uint4 LA[NSP];
    __shared__ uint4 LB[NSP];
    __shared__ uint4 LC[NSP];
    __shared__ float red[4];

    int blk = blockIdx.x;
    int b = blk >> 7;
    int tile = blk & 127;
    int ty0 = (tile >> 4) * TSY;
    int tx0 = (tile & 15) * TSX;
    int tid = threadIdx.x;

    const unsigned int* Qb = Q + (size_t)b * NP * HW;
    const uint2* Ib = IQ2 + (size_t)b * HW;

    for (int s = tid; s < NS; s += 256) {
        int ly = s / HX;
        int lx = s - ly * HX;
        int p  = ly * HXP + lx;
        int gy = ty0 + ly - R;
        int gx = tx0 + lx - R;
        bool in = ((unsigned)gy < (unsigned)H) && ((unsigned)gx < (unsigned)W);
        int g = gy * W + gx;
        unsigned int u[NP];
#pragma unroll
        for (int k = 0; k < NP; ++k) u[k] = in ? Qb[k*HW + g] : 0u;
        uint2 rgb = in ? Ib[g] : make_uint2(0u, 0u);
        LA[p] = make_uint4(u[0], u[1], u[2], u[3]);
        LB[p] = make_uint4(u[4], u[5], u[6], u[7]);
        unsigned int c2 = (u[10] & 0xffffu) | (rgb.x << 16);   // (ch20, r)
        unsigned int c3 = (rgb.x >> 16) | (rgb.y << 16);       // (g, b)
        LC[p] = make_uint4(u[8], u[9], c2, c3);
    }
    __syncthreads();

    int x = tid & 15;
    int ry = tid >> 4;
    int r0 = 2 * ry;
    int cp0 = (r0 + R) * HXP + x + R;
    int g0 = (ty0 + r0) * W + (tx0 + x);

    // --- epilogue prefetch: issue U/MG loads before the tap loop ---
    const unsigned int* Ub = Upk + (size_t)b * NP * HW;
    const unsigned int* Mb = MG + (size_t)b * NP * HW;
    unsigned int pfU[2][NP], pfM[2][NP];
#pragma unroll
    for (int k = 0; k < NP; ++k) {
        pfU[0][k] = Ub[k*HW + g0];       pfM[0][k] = Mb[k*HW + g0];
        pfU[1][k] = Ub[k*HW + g0 + W];   pfM[1][k] = Mb[k*HW + g0 + W];
    }

    float cr0, cg0, cb0, cr1, cg1, cb1;
    {
        U4 cc; cc.u = LC[cp0];
        Hu hz; hz.u32 = cc.u.z;  Hu hw2; hw2.u32 = cc.u.w;
        cr0 = __half2float(__high2half(hz.h));
        cg0 = __half2float(__low2half(hw2.h));
        cb0 = __half2float(__high2half(hw2.h));
        cc.u = LC[cp0 + HXP];
        hz.u32 = cc.u.z;  hw2.u32 = cc.u.w;
        cr1 = __half2float(__high2half(hz.h));
        cg1 = __half2float(__low2half(hw2.h));
        cb1 = __half2float(__high2half(hw2.h));
    }
    // ss1 = ss0 + 2*d0.DC + |DC|^2  (DC = c1 - c0, per-thread constant)
    float DCr = cr1 - cr0, DCg = cg1 - cg0, DCb = cb1 - cb0;
    float DR2 = 2.f * DCr, DG2 = 2.f * DCg, DB2 = 2.f * DCb;
    float DC2 = DCr*DCr + DCg*DCg + DCb*DCb;

    float kxl[13];
#pragma unroll
    for (int j = 0; j < 13; ++j)
        kxl[j] = -(float)((j - 6) * (j - 6)) * C2F;

    __half2 m0[NP], m1[NP];
#pragma unroll
    for (int k = 0; k < NP; ++k) { m0[k] = __float2half2_rn(0.f); m1[k] = m0[k]; }
    float ws0 = 0.f, ws1 = 0.f;

    for (int dyy = -R; dyy <= R + 1; ++dyy) {
        int lrow = cp0 + dyy * HXP;
        float a0 = (dyy <= R) ? -(float)(dyy * dyy) * C2F : -1e30f;
        int d1 = dyy - 1;
        float a1 = (d1 >= -R) ? -(float)(d1 * d1) * C2F : -1e30f;
        float rowA0[13], rowA1[13];
#pragma unroll
        for (int j = 0; j < 13; ++j) { rowA0[j] = a0 + kxl[j]; rowA1[j] = a1 + kxl[j]; }
        if (dyy == 0) rowA0[6] = -1e30f;   // exact center exclusion (w=0)
        if (dyy == 1) rowA1[6] = -1e30f;
#pragma unroll
        for (int dx = -R; dx <= R; ++dx) {
            int p = lrow + dx;
            U4 A, Bq, Cq;
            A.u  = LA[p];
            Bq.u = LB[p];
            Cq.u = LC[p];
            Hu hz; hz.u32 = Cq.u.z;  Hu hw2; hw2.u32 = Cq.u.w;
            float pr = __half2float(__high2half(hz.h));
            float pg = __half2float(__low2half(hw2.h));
            float pb = __half2float(__high2half(hw2.h));
            float d0r = cr0 - pr, d0g = cg0 - pg, d0b = cb0 - pb;
            float ss0 = fmaf(d0r, d0r, fmaf(d0g, d0g, d0b * d0b));
            float ss1 = fmaf(DR2, d0r, fmaf(DG2, d0g, fmaf(DB2, d0b, ss0 + DC2)));
            float w0 = fexp2(fmaf(ss0, -C2F, rowA0[dx + 6]));
            float w1 = fexp2(fmaf(ss1, -C2F, rowA1[dx + 6]));
            ws0 += w0; ws1 += w1;
            __half2 wh0 = __float2half2_rn(w0);
            __half2 wh1 = __float2half2_rn(w1);
            m0[0] = __hfma2(wh0, A.h[0], m0[0]);   m1[0] = __hfma2(wh1, A.h[0], m1[0]);
            m0[1] = __hfma2(wh0, A.h[1], m0[1]);   m1[1] = __hfma2(wh1, A.h[1], m1[1]);
            m0[2] = __hfma2(wh0, A.h[2], m0[2]);   m1[2] = __hfma2(wh1, A.h[2], m1[2]);
            m0[3] = __hfma2(wh0, A.h[3], m0[3]);   m1[3] = __hfma2(wh1, A.h[3], m1[3]);
            m0[4] = __hfma2(wh0, Bq.h[0], m0[4]);  m1[4] = __hfma2(wh1, Bq.h[0], m1[4]);
            m0[5] = __hfma2(wh0, Bq.h[1], m0[5]);  m1[5] = __hfma2(wh1, Bq.h[1], m1[5]);
            m0[6] = __hfma2(wh0, Bq.h[2], m0[6]);  m1[6] = __hfma2(wh1, Bq.h[2], m1[6]);
            m0[7] = __hfma2(wh0, Bq.h[3], m0[7]);  m1[7] = __hfma2(wh1, Bq.h[3], m1[7]);
            m0[8] = __hfma2(wh0, Cq.h[0], m0[8]);  m1[8] = __hfma2(wh1, Cq.h[0], m1[8]);
            m0[9] = __hfma2(wh0, Cq.h[1], m0[9]);  m1[9] = __hfma2(wh1, Cq.h[1], m1[9]);
            m0[10] = __hfma2(wh0, Cq.h[2], m0[10]); m1[10] = __hfma2(wh1, Cq.h[2], m1[10]);
        }
    }

    // Epilogue: softmax update (write Q) or NLL (last iteration)
    unsigned int* Qo = Qn + (size_t)b * NP * HW;

    float nll = 0.f;
#pragma unroll
    for (int px = 0; px < 2; ++px) {
        const __half2* m = px ? m1 : m0;
        float inv = 1.f / ((px ? ws1 : ws0) + 1e-8f);
        int g = g0 + px * W;
        float sv[C];
        float mm = -1e30f;
#pragma unroll
        for (int k = 0; k < NP; ++k) {
            float2 mf = __half22float2(m[k]);
            Hu mgu; mgu.u32 = pfM[px][k];
            float2 mgf = __half22float2(mgu.h);
            Hu uu; uu.u32 = pfU[px][k];
            float2 uf = __half22float2(uu.h);
            int c0 = 2 * k;
            float v0 = -uf.x + 3.f * mgf.x + 10.f * (mf.x * inv);
            sv[c0] = v0; mm = fmaxf(mm, v0);
            if (c0 + 1 < C) {
                float v1 = -uf.y + 3.f * mgf.y + 10.f * (mf.y * inv);
                sv[c0+1] = v1; mm = fmaxf(mm, v1);
            }
        }
        float s = 0.f;
#pragma unroll
        for (int c = 0; c < C; ++c) { sv[c] = __expf(sv[c] - mm); s += sv[c]; }
        if (labels) {
            int lab = labels[(size_t)b * HW + g];
            float qsum = 0.f, ql = 1e-8f;
#pragma unroll
            for (int c = 0; c < C; ++c) {
                float qc = sv[c] / s + 1e-8f;
                qsum += qc;
                if (c == lab) ql = qc;
            }
            nll += __logf(qsum) - __logf(ql);
        } else {
            float is = 1.f / s;
#pragma unroll
            for (int k = 0; k < NP; ++k) {
                float a = sv[2*k] * is;
                float bb = (2*k + 1 < C) ? sv[2*k + 1] * is : 0.f;
                Hu xh; xh.h = __floats2half2_rn(a, bb);
                Qo[k*HW + g] = xh.u32;
            }
        }
    }

    if (labels) {
#pragma unroll
        for (int off = 32; off > 0; off >>= 1) nll += __shfl_down(nll, off);
        int lane = tid & 63, wv = tid >> 6;
        if (lane == 0) red[wv] = nll;
        __syncthreads();
        if (tid == 0) part[blk] = red[0] + red[1] + red[2] + red[3];
    }
}

// ---------------------------------------------------------------------------
__global__ __launch_bounds__(256) void k_final(const float* __restrict__ part,
                                               float* __restrict__ out) {
    int tid = threadIdx.x;
    float s = part[tid] + part[tid + 256];
#pragma unroll
    for (int off = 32; off > 0; off >>= 1) s += __shfl_down(s, off);
    __shared__ float red[4];
    int lane = tid & 63, wv = tid >> 6;
    if (lane == 0) red[wv] = s;
    __syncthreads();
    if (tid == 0) out[0] = (red[0] + red[1] + red[2] + red[3]) / (float)NPIX;
}

// ---------------------------------------------------------------------------
extern "C" void kernel_launch(void* const* d_in, const int* in_sizes, int n_in,
                              void* d_out, int out_size, void* d_ws, size_t ws_size,
                              hipStream_t stream) {
    const float* logits = (const float*)d_in[0];
    const float* images = (const float*)d_in[1];
    const int*   labels = (const int*)d_in[2];
    float* out = (float*)d_out;

    unsigned int* ws = (unsigned int*)d_ws;
    unsigned int* Upk = ws;                     // NB2
    unsigned int* QA  = ws +   (size_t)NB2;     // NB2
    unsigned int* QB  = ws + 2*(size_t)NB2;     // NB2
    unsigned int* Mpk = ws + 3*(size_t)NB2;     // NB2
    uint2*        IQ2 = (uint2*)(ws + 4*(size_t)NB2);    // NPIX uint2
    float*        KT  = (float*)(IQ2 + (size_t)NPIX);    // 64 f32
    float*        PART = KT + 64;                        // 512 f32

    k_ktab<<<1, 64, 0, stream>>>(KT);
    k_prep<<<NPIX/256, 256, 0, stream>>>(images, IQ2);
    k_init<<<NPIX/256, 256, 0, stream>>>(logits, Upk, QA);

    unsigned int* cur = QA;
    unsigned int* oth = QB;
    for (int it = 0; it < 5; ++it) {
        k_gauss<<<B*NP*16, 256, 0, stream>>>(cur, Mpk, KT);
        k_update<<<B*128, 256, 0, stream>>>(cur, Upk, Mpk, IQ2, oth,
                                            (it == 4) ? labels : nullptr, PART);
        unsigned int* t = cur; cur = oth; oth = t;
    }

    k_final<<<1, 256, 0, stream>>>(PART, out);
    (void)in_sizes; (void)n_in; (void)out_size; (void)ws_size;
}